// Round 3
// baseline (507.113 us; speedup 1.0000x reference)
//
#include <hip/hip_runtime.h>
#include <hip/hip_bf16.h>
#include <hip/hip_cooperative_groups.h>

namespace cg = cooperative_groups;

#define H 8
#define HD 32
#define DD 256
#define NEG_SLOPE 0.2f

typedef short bf16x8 __attribute__((ext_vector_type(8)));
typedef float f32x4 __attribute__((ext_vector_type(4)));

__device__ __forceinline__ unsigned short f2bf(float f) {
    unsigned int u = __float_as_uint(f);
    unsigned int r = (u + 0x7fffu + ((u >> 16) & 1u)) >> 16;
    return (unsigned short)r;
}
__device__ __forceinline__ float bf2f(unsigned short b) {
    return __uint_as_float(((unsigned int)b) << 16);
}

#define GLOAD_LDS16(g, s)                                                        \
    __builtin_amdgcn_global_load_lds((const __attribute__((address_space(1))) void*)(g), \
                                     (__attribute__((address_space(3))) void*)(s), 16, 0, 0)

// ---------------- fused prep: weight transposes + zero cnt/fill + conv x -----
// blocks [0,256) Wt, [256,512) W1t, [512,768) W2t,
// [768,768+ZB) zero cnt, [768+ZB,768+2ZB) zero fill, rest conv_x
__global__ __launch_bounds__(256) void prep(const float* __restrict__ x, unsigned short* __restrict__ xb,
                                            const float* __restrict__ W, unsigned short* __restrict__ Wt,
                                            const float* __restrict__ W1, unsigned short* __restrict__ W1t,
                                            const float* __restrict__ W2, unsigned short* __restrict__ W2t,
                                            int* __restrict__ cnt, int* __restrict__ fill,
                                            int N, int n4, int ZB) {
    int b = blockIdx.x;
    int tid = threadIdx.x;
    if (b < 768) {
        const float* src = (b < 256) ? W : (b < 512) ? W1 : W2;
        unsigned short* dst = (b < 256) ? Wt : (b < 512) ? W1t : W2t;
        int i = (b & 255) * 256 + tid;
        int n = i >> 8, k = i & 255;
        dst[i] = f2bf(src[k * 256 + n]);
    } else if (b < 768 + 2 * ZB) {
        int rb = b - 768;
        int* dst = (rb < ZB) ? cnt : fill;
        int i = (rb % ZB) * 256 + tid;
        if (i < N) dst[i] = 0;
    } else {
        int i = (b - 768 - 2 * ZB) * 256 + tid;
        if (i < n4) {
            float4 v = ((const float4*)x)[i];
            ushort4 o;
            o.x = f2bf(v.x); o.y = f2bf(v.y); o.z = f2bf(v.z); o.w = f2bf(v.w);
            ((ushort4*)xb)[i] = o;
        }
    }
}

// ---------------- bf16 MFMA GEMM: C[M,256] = A[M,256] @ B, Bt=[n][k] ---------
// block tile 128x128, BK=32, 4 waves (2x2 of 64x64), 16x16x32 bf16 MFMA
enum { E_NONE = 0, E_BIAS_RELU = 1, E_BIAS = 2 };

template <int EPI, bool OBF, bool ATTN>
__global__ __launch_bounds__(256) void gemm_bf16(const unsigned short* __restrict__ A,
                                                 const unsigned short* __restrict__ Bt,
                                                 const float* __restrict__ bias,
                                                 void* __restrict__ Cout, int M,
                                                 const float* __restrict__ att_s,
                                                 const float* __restrict__ att_d,
                                                 float* __restrict__ a_srcO,
                                                 float* __restrict__ a_dstO) {
    constexpr int K = 256;
    __shared__ __align__(16) unsigned short Als[4096];  // [q][m][8] : 4*128*8
    __shared__ __align__(16) unsigned short Bls[4096];  // [q][n][8]

    const int tid = threadIdx.x;
    const int l = tid & 63;
    const int w = tid >> 6;       // wave 0..3
    const int wr = w >> 1, wc = w & 1;
    const int row0 = blockIdx.x * 128;
    const int col0 = blockIdx.y * 128;

    const unsigned short* ga0 = A + (size_t)min(row0 + l, M - 1) * K + w * 8;
    const unsigned short* ga1 = A + (size_t)min(row0 + 64 + l, M - 1) * K + w * 8;
    const unsigned short* gb0 = Bt + (size_t)(col0 + l) * K + w * 8;
    const unsigned short* gb1 = Bt + (size_t)(col0 + 64 + l) * K + w * 8;
    unsigned short* la0 = &Als[(w * 128 + 0) * 8];
    unsigned short* la1 = &Als[(w * 128 + 64) * 8];
    unsigned short* lb0 = &Bls[(w * 128 + 0) * 8];
    unsigned short* lb1 = &Bls[(w * 128 + 64) * 8];

    const int q = l >> 4, r16 = l & 15;

    f32x4 zero = {0.f, 0.f, 0.f, 0.f};
    f32x4 acc[4][4];
#pragma unroll
    for (int i = 0; i < 4; i++)
#pragma unroll
        for (int j = 0; j < 4; j++) acc[i][j] = zero;

    for (int kk = 0; kk < K; kk += 32) {
        GLOAD_LDS16(ga0 + kk, la0);
        GLOAD_LDS16(ga1 + kk, la1);
        GLOAD_LDS16(gb0 + kk, lb0);
        GLOAD_LDS16(gb1 + kk, lb1);
        __syncthreads();
        bf16x8 af[4], bfr[4];
#pragma unroll
        for (int i = 0; i < 4; i++)
            af[i] = *(const bf16x8*)&Als[(q * 128 + wr * 64 + i * 16 + r16) * 8];
#pragma unroll
        for (int j = 0; j < 4; j++)
            bfr[j] = *(const bf16x8*)&Bls[(q * 128 + wc * 64 + j * 16 + r16) * 8];
#pragma unroll
        for (int i = 0; i < 4; i++)
#pragma unroll
            for (int j = 0; j < 4; j++)
                acc[i][j] = __builtin_amdgcn_mfma_f32_16x16x32_bf16(af[i], bfr[j], acc[i][j], 0, 0, 0);
        __syncthreads();
    }

    // epilogue: row = orow + i*16 + r, col = ocol + j*16
    const int orow = row0 + wr * 64 + q * 4;
    const int ocol = col0 + wc * 64 + r16;

    // attention-score fusion: head hA covers local cols [0,32) of this wave's
    // 64-col span (j=0,1), hB covers [32,64) (j=2,3). colmod = (j&1)*16 + r16.
    float aws0, aws1, aws2, aws3, awd0, awd1, awd2, awd3;
    int hA = 0, hB = 0;
    if (ATTN) {
        hA = blockIdx.y * 4 + wc * 2;
        hB = hA + 1;
        aws0 = att_s[hA * HD + r16];
        aws1 = att_s[hA * HD + 16 + r16];
        aws2 = att_s[hB * HD + r16];
        aws3 = att_s[hB * HD + 16 + r16];
        awd0 = att_d[hA * HD + r16];
        awd1 = att_d[hA * HD + 16 + r16];
        awd2 = att_d[hB * HD + r16];
        awd3 = att_d[hB * HD + 16 + r16];
    }

#pragma unroll
    for (int i = 0; i < 4; i++) {
#pragma unroll
        for (int r = 0; r < 4; r++) {
            int row = orow + i * 16 + r;
            if (row < M) {
#pragma unroll
                for (int j = 0; j < 4; j++) {
                    int col = ocol + j * 16;
                    float v = acc[i][j][r];
                    if (EPI != E_NONE) v += bias[col];
                    if (EPI == E_BIAS_RELU) v = fmaxf(v, 0.f);
                    if (OBF)
                        ((unsigned short*)Cout)[(size_t)row * 256 + col] = f2bf(v);
                    else
                        ((float*)Cout)[(size_t)row * 256 + col] = v;
                }
            }
            if (ATTN) {
                float v0 = acc[i][0][r], v1 = acc[i][1][r];
                float v2 = acc[i][2][r], v3 = acc[i][3][r];
                float ps0 = v0 * aws0 + v1 * aws1;
                float ps1 = v2 * aws2 + v3 * aws3;
                float pd0 = v0 * awd0 + v1 * awd1;
                float pd1 = v2 * awd2 + v3 * awd3;
#pragma unroll
                for (int m = 1; m < 16; m <<= 1) {
                    ps0 += __shfl_xor(ps0, m, 64);
                    ps1 += __shfl_xor(ps1, m, 64);
                    pd0 += __shfl_xor(pd0, m, 64);
                    pd1 += __shfl_xor(pd1, m, 64);
                }
                if (r16 == 0 && row < M) {
                    a_srcO[row * H + hA] = ps0;
                    a_srcO[row * H + hB] = ps1;
                    a_dstO[row * H + hA] = pd0;
                    a_dstO[row * H + hB] = pd1;
                }
            }
        }
    }
}

// ---------------- cooperative CSR build: hist + scan + scatter ---------------
__global__ __launch_bounds__(1024) void csr_build(const int* __restrict__ ei,
                                                  int* __restrict__ cnt, int* __restrict__ fill,
                                                  int* __restrict__ row_ptr, int* __restrict__ bsum,
                                                  int* __restrict__ src_sorted,
                                                  int N, int E, int nb) {
    cg::grid_group grid = cg::this_grid();
    const int tid = threadIdx.x;
    const int b = blockIdx.x;
    const int gsz = gridDim.x * 1024;
    const int gi = b * 1024 + tid;
    __shared__ int ws[4];

    // 1. histogram (cnt pre-zeroed by prep kernel)
    for (int e = gi; e < E; e += gsz) atomicAdd(&cnt[ei[E + e]], 1);
    grid.sync();

    // 2a. per-block local inclusive scan of 256-element chunk
    const int i5 = b * 256 + tid;
    const int lane = tid & 63, wv = tid >> 6;
    int v = (tid < 256 && i5 < N) ? cnt[i5] : 0;
    int sv = v;
#pragma unroll
    for (int off = 1; off < 64; off <<= 1) {
        int t = __shfl_up(sv, off, 64);
        if (lane >= off) sv += t;
    }
    if (tid < 256 && lane == 63) ws[wv] = sv;
    __syncthreads();
    int woff = 0;
    if (tid < 256) {
#pragma unroll
        for (int k = 0; k < 4; k++)
            if (k < wv) woff += ws[k];
    }
    int incl = sv + woff;
    if (tid < 256 && i5 < N) row_ptr[i5 + 1] = incl;
    if (tid == 0) bsum[b] = ws[0] + ws[1] + ws[2] + ws[3];
    grid.sync();

    // 2b. block 0 wave 0: exclusive scan of block totals
    if (b == 0 && tid < 64) {
        int carry = 0;
        for (int base = 0; base < nb; base += 64) {
            int idx = base + tid;
            int v2 = (idx < nb) ? bsum[idx] : 0;
            int s = v2;
#pragma unroll
            for (int off = 1; off < 64; off <<= 1) {
                int t = __shfl_up(s, off, 64);
                if (lane >= off) s += t;
            }
            int excl = s - v2 + carry;
            if (idx < nb) bsum[idx] = excl;
            carry += __shfl(s, 63, 64);
        }
    }
    grid.sync();

    // 2c. add block offsets
    if (tid < 256 && i5 < N) row_ptr[i5 + 1] = incl + bsum[b];
    if (b == 0 && tid == 0) row_ptr[0] = 0;
    grid.sync();

    // 3. scatter (fill pre-zeroed by prep kernel)
    for (int e = gi; e < E; e += gsz) {
        int s = ei[e];
        int d = ei[E + e];
        int pos = row_ptr[d] + atomicAdd(&fill[d], 1);
        src_sorted[pos] = s;
    }
}

// ---------------- fused softmax-aggregate + bias + residual + LN -------------
__global__ __launch_bounds__(256) void aggregate_ln(
    const unsigned short* __restrict__ xp, const float* __restrict__ x,
    const float* __restrict__ a_src, const float* __restrict__ a_dst,
    const int* __restrict__ row_ptr, const int* __restrict__ src_sorted,
    const float* __restrict__ bias, const float* __restrict__ ln_g,
    const float* __restrict__ ln_b, unsigned short* __restrict__ hn, int N) {
    int wave = threadIdx.x >> 6;
    int lane = threadIdx.x & 63;
    int n = blockIdx.x * 4 + wave;
    if (n >= N) return;
    int h = lane >> 3;

    float adst = a_dst[n * H + h];
    float e0 = a_src[n * H + h] + adst;
    e0 = (e0 > 0.f) ? e0 : NEG_SLOPE * e0;
    float ex = __expf(e0);
    ushort4 u = *(const ushort4*)(xp + (size_t)n * DD + lane * 4);
    float acc0 = ex * bf2f(u.x), acc1 = ex * bf2f(u.y);
    float acc2 = ex * bf2f(u.z), acc3 = ex * bf2f(u.w);
    float denom = ex;

    int beg = row_ptr[n], end = row_ptr[n + 1];
    int i = beg;
    for (; i + 1 < end; i += 2) {
        int s0 = src_sorted[i], s1 = src_sorted[i + 1];
        float es0 = a_src[s0 * H + h], es1 = a_src[s1 * H + h];
        ushort4 u0 = *(const ushort4*)(xp + (size_t)s0 * DD + lane * 4);
        ushort4 u1 = *(const ushort4*)(xp + (size_t)s1 * DD + lane * 4);
        float e0a = es0 + adst; e0a = (e0a > 0.f) ? e0a : NEG_SLOPE * e0a;
        float e1a = es1 + adst; e1a = (e1a > 0.f) ? e1a : NEG_SLOPE * e1a;
        float w0 = __expf(e0a), w1 = __expf(e1a);
        acc0 += w0 * bf2f(u0.x) + w1 * bf2f(u1.x);
        acc1 += w0 * bf2f(u0.y) + w1 * bf2f(u1.y);
        acc2 += w0 * bf2f(u0.z) + w1 * bf2f(u1.z);
        acc3 += w0 * bf2f(u0.w) + w1 * bf2f(u1.w);
        denom += w0 + w1;
    }
    if (i < end) {
        int s0 = src_sorted[i];
        float es0 = a_src[s0 * H + h];
        ushort4 u0 = *(const ushort4*)(xp + (size_t)s0 * DD + lane * 4);
        float e0a = es0 + adst; e0a = (e0a > 0.f) ? e0a : NEG_SLOPE * e0a;
        float w0 = __expf(e0a);
        acc0 += w0 * bf2f(u0.x);
        acc1 += w0 * bf2f(u0.y);
        acc2 += w0 * bf2f(u0.z);
        acc3 += w0 * bf2f(u0.w);
        denom += w0;
    }
    float inv = 1.f / (denom + 1e-16f);
    float4 bb = *(const float4*)(bias + lane * 4);
    float4 xr = *(const float4*)(x + (size_t)n * DD + lane * 4);
    float r0 = acc0 * inv + bb.x + xr.x;
    float r1 = acc1 * inv + bb.y + xr.y;
    float r2 = acc2 * inv + bb.z + xr.z;
    float r3 = acc3 * inv + bb.w + xr.w;

    float s = r0 + r1 + r2 + r3;
#pragma unroll
    for (int m = 1; m < 64; m <<= 1) s += __shfl_xor(s, m, 64);
    float mu = s * (1.f / 256.f);
    float d0 = r0 - mu, d1 = r1 - mu, d2 = r2 - mu, d3 = r3 - mu;
    float qv = d0 * d0 + d1 * d1 + d2 * d2 + d3 * d3;
#pragma unroll
    for (int m = 1; m < 64; m <<= 1) qv += __shfl_xor(qv, m, 64);
    float rstd = rsqrtf(qv * (1.f / 256.f) + 1e-5f);
    float4 g = *(const float4*)(ln_g + lane * 4);
    float4 b = *(const float4*)(ln_b + lane * 4);
    ushort4 o;
    o.x = f2bf(d0 * rstd * g.x + b.x);
    o.y = f2bf(d1 * rstd * g.y + b.y);
    o.z = f2bf(d2 * rstd * g.z + b.z);
    o.w = f2bf(d3 * rstd * g.w + b.w);
    *(ushort4*)(hn + (size_t)n * DD + lane * 4) = o;
}

// ---------------- launch ------------------------------------------------------
extern "C" void kernel_launch(void* const* d_in, const int* in_sizes, int n_in,
                              void* d_out, int out_size, void* d_ws, size_t ws_size,
                              hipStream_t stream) {
    const float* x = (const float*)d_in[0];
    const int* edge_index = (const int*)d_in[1];
    const float* W = (const float*)d_in[3];
    const float* att_src = (const float*)d_in[4];
    const float* att_dst = (const float*)d_in[5];
    const float* bias = (const float*)d_in[6];
    const float* ln_g = (const float*)d_in[7];
    const float* ln_b = (const float*)d_in[8];
    const float* W1 = (const float*)d_in[9];
    const float* b1 = (const float*)d_in[10];
    const float* W2 = (const float*)d_in[11];
    const float* b2 = (const float*)d_in[12];

    const int N = in_sizes[0] / DD;
    const int E = in_sizes[1] / 2;

    // workspace carve-up
    char* p = (char*)d_ws;
    auto carve = [&](size_t bytes) {
        char* r = p;
        p += (bytes + 255) & ~(size_t)255;
        return r;
    };
    unsigned short* x_bf = (unsigned short*)carve((size_t)N * DD * 2);
    unsigned short* xp_bf = (unsigned short*)carve((size_t)N * DD * 2);
    unsigned short* hn_bf = (unsigned short*)carve((size_t)N * DD * 2);
    float* a_src = (float*)carve((size_t)N * H * 4);
    float* a_dst = (float*)carve((size_t)N * H * 4);
    int* row_ptr = (int*)carve((size_t)(N + 1) * 4);
    int* cnt = (int*)carve((size_t)N * 4);
    int* fill = (int*)carve((size_t)N * 4);
    int* bsum = (int*)carve(256 * 4);
    int* src_sorted = (int*)carve((size_t)E * 4);
    unsigned short* Wt = (unsigned short*)carve(65536 * 2);
    unsigned short* W1t = (unsigned short*)carve(65536 * 2);
    unsigned short* W2t = (unsigned short*)carve(65536 * 2);
    unsigned short* t1_bf = x_bf;  // reuse after GEMM1

    const int n4 = N * DD / 4;
    const int ZB = (N + 255) / 256;  // 196

    // 1. prep: weight transposes + zero cnt/fill + x->bf16  (1 launch)
    int prep_blocks = 768 + 2 * ZB + (n4 + 255) / 256;
    prep<<<prep_blocks, 256, 0, stream>>>(x, x_bf, W, Wt, W1, W1t, W2, W2t, cnt, fill, N, n4, ZB);

    dim3 ggrid((N + 127) / 128, 2);

    // 2. xp = x @ W (bf16 out) + fused attention scores  (1 launch)
    gemm_bf16<E_NONE, true, true><<<ggrid, 256, 0, stream>>>(
        x_bf, Wt, nullptr, xp_bf, N, att_src, att_dst, a_src, a_dst);

    // 3. cooperative CSR build: hist + scan + scatter  (1 launch)
    int nb = ZB;  // 196 blocks, co-resident on 256 CUs
    {
        const int* ei = edge_index;
        int Nv = N, Ev = E, nbv = nb;
        void* args[] = {(void*)&ei, (void*)&cnt, (void*)&fill, (void*)&row_ptr,
                        (void*)&bsum, (void*)&src_sorted, (void*)&Nv, (void*)&Ev, (void*)&nbv};
        hipLaunchCooperativeKernel((void*)csr_build, dim3(nb), dim3(1024), args, 0, stream);
    }

    // 4. fused aggregate + LN (bf16 out)  (1 launch)
    aggregate_ln<<<(N + 3) / 4, 256, 0, stream>>>(xp_bf, x, a_src, a_dst, row_ptr, src_sorted,
                                                  bias, ln_g, ln_b, hn_bf, N);

    // 5. FFN  (2 launches)
    gemm_bf16<E_BIAS_RELU, true, false><<<ggrid, 256, 0, stream>>>(
        hn_bf, W1t, b1, t1_bf, N, nullptr, nullptr, nullptr, nullptr);
    gemm_bf16<E_BIAS, false, false><<<ggrid, 256, 0, stream>>>(
        t1_bf, W2t, b2, d_out, N, nullptr, nullptr, nullptr, nullptr);
}

// Round 4
// 395.699 us; speedup vs baseline: 1.2816x; 1.2816x over previous
//
#include <hip/hip_runtime.h>
#include <hip/hip_bf16.h>

#define H 8
#define HD 32
#define DD 256
#define NEG_SLOPE 0.2f

typedef short bf16x8 __attribute__((ext_vector_type(8)));
typedef float f32x4 __attribute__((ext_vector_type(4)));

__device__ __forceinline__ unsigned short f2bf(float f) {
    unsigned int u = __float_as_uint(f);
    unsigned int r = (u + 0x7fffu + ((u >> 16) & 1u)) >> 16;
    return (unsigned short)r;
}
__device__ __forceinline__ float bf2f(unsigned short b) {
    return __uint_as_float(((unsigned int)b) << 16);
}

#define GLOAD_LDS16(g, s)                                                        \
    __builtin_amdgcn_global_load_lds((const __attribute__((address_space(1))) void*)(g), \
                                     (__attribute__((address_space(3))) void*)(s), 16, 0, 0)

// ---------------- fused prep: weight transposes + zero cnt/fill + conv x -----
// blocks [0,256) Wt, [256,512) W1t, [512,768) W2t,
// [768,768+ZB) zero cnt, [768+ZB,768+2ZB) zero fill, rest conv_x
__global__ __launch_bounds__(256) void prep(const float* __restrict__ x, unsigned short* __restrict__ xb,
                                            const float* __restrict__ W, unsigned short* __restrict__ Wt,
                                            const float* __restrict__ W1, unsigned short* __restrict__ W1t,
                                            const float* __restrict__ W2, unsigned short* __restrict__ W2t,
                                            int* __restrict__ cnt, int* __restrict__ fill,
                                            int N, int n4, int ZB) {
    int b = blockIdx.x;
    int tid = threadIdx.x;
    if (b < 768) {
        const float* src = (b < 256) ? W : (b < 512) ? W1 : W2;
        unsigned short* dst = (b < 256) ? Wt : (b < 512) ? W1t : W2t;
        int i = (b & 255) * 256 + tid;
        int n = i >> 8, k = i & 255;
        dst[i] = f2bf(src[k * 256 + n]);
    } else if (b < 768 + 2 * ZB) {
        int rb = b - 768;
        int* dst = (rb < ZB) ? cnt : fill;
        int i = (rb % ZB) * 256 + tid;
        if (i < N) dst[i] = 0;
    } else {
        int i = (b - 768 - 2 * ZB) * 256 + tid;
        if (i < n4) {
            float4 v = ((const float4*)x)[i];
            ushort4 o;
            o.x = f2bf(v.x); o.y = f2bf(v.y); o.z = f2bf(v.z); o.w = f2bf(v.w);
            ((ushort4*)xb)[i] = o;
        }
    }
}

// ---------------- bf16 MFMA GEMM: C[M,256] = A[M,256] @ B, Bt=[n][k] ---------
// block tile 128x128, BK=32, 4 waves (2x2 of 64x64), 16x16x32 bf16 MFMA
enum { E_NONE = 0, E_BIAS_RELU = 1, E_BIAS = 2 };

template <int EPI, bool OBF, bool ATTN>
__global__ __launch_bounds__(256) void gemm_bf16(const unsigned short* __restrict__ A,
                                                 const unsigned short* __restrict__ Bt,
                                                 const float* __restrict__ bias,
                                                 void* __restrict__ Cout, int M,
                                                 const float* __restrict__ att_s,
                                                 const float* __restrict__ att_d,
                                                 float* __restrict__ a_srcO,
                                                 float* __restrict__ a_dstO) {
    constexpr int K = 256;
    __shared__ __align__(16) unsigned short Als[4096];  // [q][m][8] : 4*128*8
    __shared__ __align__(16) unsigned short Bls[4096];  // [q][n][8]

    const int tid = threadIdx.x;
    const int l = tid & 63;
    const int w = tid >> 6;       // wave 0..3
    const int wr = w >> 1, wc = w & 1;
    const int row0 = blockIdx.x * 128;
    const int col0 = blockIdx.y * 128;

    const unsigned short* ga0 = A + (size_t)min(row0 + l, M - 1) * K + w * 8;
    const unsigned short* ga1 = A + (size_t)min(row0 + 64 + l, M - 1) * K + w * 8;
    const unsigned short* gb0 = Bt + (size_t)(col0 + l) * K + w * 8;
    const unsigned short* gb1 = Bt + (size_t)(col0 + 64 + l) * K + w * 8;
    unsigned short* la0 = &Als[(w * 128 + 0) * 8];
    unsigned short* la1 = &Als[(w * 128 + 64) * 8];
    unsigned short* lb0 = &Bls[(w * 128 + 0) * 8];
    unsigned short* lb1 = &Bls[(w * 128 + 64) * 8];

    const int q = l >> 4, r16 = l & 15;

    f32x4 zero = {0.f, 0.f, 0.f, 0.f};
    f32x4 acc[4][4];
#pragma unroll
    for (int i = 0; i < 4; i++)
#pragma unroll
        for (int j = 0; j < 4; j++) acc[i][j] = zero;

    for (int kk = 0; kk < K; kk += 32) {
        GLOAD_LDS16(ga0 + kk, la0);
        GLOAD_LDS16(ga1 + kk, la1);
        GLOAD_LDS16(gb0 + kk, lb0);
        GLOAD_LDS16(gb1 + kk, lb1);
        __syncthreads();
        bf16x8 af[4], bfr[4];
#pragma unroll
        for (int i = 0; i < 4; i++)
            af[i] = *(const bf16x8*)&Als[(q * 128 + wr * 64 + i * 16 + r16) * 8];
#pragma unroll
        for (int j = 0; j < 4; j++)
            bfr[j] = *(const bf16x8*)&Bls[(q * 128 + wc * 64 + j * 16 + r16) * 8];
#pragma unroll
        for (int i = 0; i < 4; i++)
#pragma unroll
            for (int j = 0; j < 4; j++)
                acc[i][j] = __builtin_amdgcn_mfma_f32_16x16x32_bf16(af[i], bfr[j], acc[i][j], 0, 0, 0);
        __syncthreads();
    }

    // epilogue: row = orow + i*16 + r, col = ocol + j*16
    const int orow = row0 + wr * 64 + q * 4;
    const int ocol = col0 + wc * 64 + r16;

    // attention-score fusion: head hA covers local cols [0,32) of this wave's
    // 64-col span (j=0,1), hB covers [32,64) (j=2,3).
    float aws0, aws1, aws2, aws3, awd0, awd1, awd2, awd3;
    int hA = 0, hB = 0;
    if (ATTN) {
        hA = blockIdx.y * 4 + wc * 2;
        hB = hA + 1;
        aws0 = att_s[hA * HD + r16];
        aws1 = att_s[hA * HD + 16 + r16];
        aws2 = att_s[hB * HD + r16];
        aws3 = att_s[hB * HD + 16 + r16];
        awd0 = att_d[hA * HD + r16];
        awd1 = att_d[hA * HD + 16 + r16];
        awd2 = att_d[hB * HD + r16];
        awd3 = att_d[hB * HD + 16 + r16];
    }

#pragma unroll
    for (int i = 0; i < 4; i++) {
#pragma unroll
        for (int r = 0; r < 4; r++) {
            int row = orow + i * 16 + r;
            if (row < M) {
#pragma unroll
                for (int j = 0; j < 4; j++) {
                    int col = ocol + j * 16;
                    float v = acc[i][j][r];
                    if (EPI != E_NONE) v += bias[col];
                    if (EPI == E_BIAS_RELU) v = fmaxf(v, 0.f);
                    if (OBF)
                        ((unsigned short*)Cout)[(size_t)row * 256 + col] = f2bf(v);
                    else
                        ((float*)Cout)[(size_t)row * 256 + col] = v;
                }
            }
            if (ATTN) {
                float v0 = acc[i][0][r], v1 = acc[i][1][r];
                float v2 = acc[i][2][r], v3 = acc[i][3][r];
                float ps0 = v0 * aws0 + v1 * aws1;
                float ps1 = v2 * aws2 + v3 * aws3;
                float pd0 = v0 * awd0 + v1 * awd1;
                float pd1 = v2 * awd2 + v3 * awd3;
#pragma unroll
                for (int m = 1; m < 16; m <<= 1) {
                    ps0 += __shfl_xor(ps0, m, 64);
                    ps1 += __shfl_xor(ps1, m, 64);
                    pd0 += __shfl_xor(pd0, m, 64);
                    pd1 += __shfl_xor(pd1, m, 64);
                }
                if (r16 == 0 && row < M) {
                    a_srcO[row * H + hA] = ps0;
                    a_srcO[row * H + hB] = ps1;
                    a_dstO[row * H + hA] = pd0;
                    a_dstO[row * H + hB] = pd1;
                }
            }
        }
    }
}

// ---------------- CSR build (split kernels) ----------------------------------
__global__ void hist_kernel(const int* __restrict__ ei, int* __restrict__ counts, int E) {
    int e = blockIdx.x * blockDim.x + threadIdx.x;
    if (e < E) atomicAdd(&counts[ei[E + e]], 1);
}

__global__ __launch_bounds__(1024) void scan_block(const int* __restrict__ cnt,
                                                   int* __restrict__ row_ptr,
                                                   int* __restrict__ bsum, int N) {
    __shared__ int ws[16];
    int i = blockIdx.x * 1024 + threadIdx.x;
    int lane = threadIdx.x & 63, w = threadIdx.x >> 6;
    int v = (i < N) ? cnt[i] : 0;
    int sv = v;
#pragma unroll
    for (int off = 1; off < 64; off <<= 1) {
        int t = __shfl_up(sv, off, 64);
        if (lane >= off) sv += t;
    }
    if (lane == 63) ws[w] = sv;
    __syncthreads();
    if (w == 0) {
        int s = (lane < 16) ? ws[lane] : 0;
#pragma unroll
        for (int off = 1; off < 16; off <<= 1) {
            int t = __shfl_up(s, off, 64);
            if (lane >= off) s += t;
        }
        if (lane < 16) ws[lane] = s;
    }
    __syncthreads();
    int incl = sv + ((w > 0) ? ws[w - 1] : 0);
    if (i < N) row_ptr[i + 1] = incl;
    if (threadIdx.x == 1023) bsum[blockIdx.x] = incl;
}

__global__ void scan_partial(int* __restrict__ bsum, int nb) {
    int lane = threadIdx.x;  // 64 threads
    int v = (lane < nb) ? bsum[lane] : 0;
    int s = v;
#pragma unroll
    for (int off = 1; off < 64; off <<= 1) {
        int t = __shfl_up(s, off, 64);
        if (lane >= off) s += t;
    }
    if (lane < nb) bsum[lane] = s - v;  // exclusive
}

__global__ __launch_bounds__(1024) void scan_add(int* __restrict__ row_ptr,
                                                 const int* __restrict__ bsum, int N) {
    int i = blockIdx.x * 1024 + threadIdx.x;
    if (i == 0) row_ptr[0] = 0;
    if (i < N) row_ptr[i + 1] += bsum[blockIdx.x];
}

__global__ void scatter_kernel(const int* __restrict__ ei, const int* __restrict__ row_ptr,
                               int* __restrict__ fill, int* __restrict__ src_sorted, int E) {
    int e = blockIdx.x * blockDim.x + threadIdx.x;
    if (e >= E) return;
    int s = ei[e];
    int d = ei[E + e];
    int pos = row_ptr[d] + atomicAdd(&fill[d], 1);
    src_sorted[pos] = s;
}

// ---------------- fused softmax-aggregate + bias + residual + LN -------------
__global__ __launch_bounds__(256) void aggregate_ln(
    const unsigned short* __restrict__ xp, const float* __restrict__ x,
    const float* __restrict__ a_src, const float* __restrict__ a_dst,
    const int* __restrict__ row_ptr, const int* __restrict__ src_sorted,
    const float* __restrict__ bias, const float* __restrict__ ln_g,
    const float* __restrict__ ln_b, unsigned short* __restrict__ hn, int N) {
    int wave = threadIdx.x >> 6;
    int lane = threadIdx.x & 63;
    int n = blockIdx.x * 4 + wave;
    if (n >= N) return;
    int h = lane >> 3;

    float adst = a_dst[n * H + h];
    float e0 = a_src[n * H + h] + adst;
    e0 = (e0 > 0.f) ? e0 : NEG_SLOPE * e0;
    float ex = __expf(e0);
    ushort4 u = *(const ushort4*)(xp + (size_t)n * DD + lane * 4);
    float acc0 = ex * bf2f(u.x), acc1 = ex * bf2f(u.y);
    float acc2 = ex * bf2f(u.z), acc3 = ex * bf2f(u.w);
    float denom = ex;

    int beg = row_ptr[n], end = row_ptr[n + 1];
    int i = beg;
    for (; i + 3 < end; i += 4) {
        int s0 = src_sorted[i], s1 = src_sorted[i + 1];
        int s2 = src_sorted[i + 2], s3 = src_sorted[i + 3];
        float es0 = a_src[s0 * H + h], es1 = a_src[s1 * H + h];
        float es2 = a_src[s2 * H + h], es3 = a_src[s3 * H + h];
        ushort4 u0 = *(const ushort4*)(xp + (size_t)s0 * DD + lane * 4);
        ushort4 u1 = *(const ushort4*)(xp + (size_t)s1 * DD + lane * 4);
        ushort4 u2 = *(const ushort4*)(xp + (size_t)s2 * DD + lane * 4);
        ushort4 u3 = *(const ushort4*)(xp + (size_t)s3 * DD + lane * 4);
        float e0a = es0 + adst; e0a = (e0a > 0.f) ? e0a : NEG_SLOPE * e0a;
        float e1a = es1 + adst; e1a = (e1a > 0.f) ? e1a : NEG_SLOPE * e1a;
        float e2a = es2 + adst; e2a = (e2a > 0.f) ? e2a : NEG_SLOPE * e2a;
        float e3a = es3 + adst; e3a = (e3a > 0.f) ? e3a : NEG_SLOPE * e3a;
        float w0 = __expf(e0a), w1 = __expf(e1a);
        float w2 = __expf(e2a), w3 = __expf(e3a);
        acc0 += w0 * bf2f(u0.x) + w1 * bf2f(u1.x) + w2 * bf2f(u2.x) + w3 * bf2f(u3.x);
        acc1 += w0 * bf2f(u0.y) + w1 * bf2f(u1.y) + w2 * bf2f(u2.y) + w3 * bf2f(u3.y);
        acc2 += w0 * bf2f(u0.z) + w1 * bf2f(u1.z) + w2 * bf2f(u2.z) + w3 * bf2f(u3.z);
        acc3 += w0 * bf2f(u0.w) + w1 * bf2f(u1.w) + w2 * bf2f(u2.w) + w3 * bf2f(u3.w);
        denom += w0 + w1 + w2 + w3;
    }
    for (; i < end; i++) {
        int s0 = src_sorted[i];
        float es0 = a_src[s0 * H + h];
        ushort4 u0 = *(const ushort4*)(xp + (size_t)s0 * DD + lane * 4);
        float e0a = es0 + adst; e0a = (e0a > 0.f) ? e0a : NEG_SLOPE * e0a;
        float w0 = __expf(e0a);
        acc0 += w0 * bf2f(u0.x);
        acc1 += w0 * bf2f(u0.y);
        acc2 += w0 * bf2f(u0.z);
        acc3 += w0 * bf2f(u0.w);
        denom += w0;
    }
    float inv = 1.f / (denom + 1e-16f);
    float4 bb = *(const float4*)(bias + lane * 4);
    float4 xr = *(const float4*)(x + (size_t)n * DD + lane * 4);
    float r0 = acc0 * inv + bb.x + xr.x;
    float r1 = acc1 * inv + bb.y + xr.y;
    float r2 = acc2 * inv + bb.z + xr.z;
    float r3 = acc3 * inv + bb.w + xr.w;

    float s = r0 + r1 + r2 + r3;
#pragma unroll
    for (int m = 1; m < 64; m <<= 1) s += __shfl_xor(s, m, 64);
    float mu = s * (1.f / 256.f);
    float d0 = r0 - mu, d1 = r1 - mu, d2 = r2 - mu, d3 = r3 - mu;
    float qv = d0 * d0 + d1 * d1 + d2 * d2 + d3 * d3;
#pragma unroll
    for (int m = 1; m < 64; m <<= 1) qv += __shfl_xor(qv, m, 64);
    float rstd = rsqrtf(qv * (1.f / 256.f) + 1e-5f);
    float4 g = *(const float4*)(ln_g + lane * 4);
    float4 b = *(const float4*)(ln_b + lane * 4);
    ushort4 o;
    o.x = f2bf(d0 * rstd * g.x + b.x);
    o.y = f2bf(d1 * rstd * g.y + b.y);
    o.z = f2bf(d2 * rstd * g.z + b.z);
    o.w = f2bf(d3 * rstd * g.w + b.w);
    *(ushort4*)(hn + (size_t)n * DD + lane * 4) = o;
}

// ---------------- launch ------------------------------------------------------
extern "C" void kernel_launch(void* const* d_in, const int* in_sizes, int n_in,
                              void* d_out, int out_size, void* d_ws, size_t ws_size,
                              hipStream_t stream) {
    const float* x = (const float*)d_in[0];
    const int* edge_index = (const int*)d_in[1];
    const float* W = (const float*)d_in[3];
    const float* att_src = (const float*)d_in[4];
    const float* att_dst = (const float*)d_in[5];
    const float* bias = (const float*)d_in[6];
    const float* ln_g = (const float*)d_in[7];
    const float* ln_b = (const float*)d_in[8];
    const float* W1 = (const float*)d_in[9];
    const float* b1 = (const float*)d_in[10];
    const float* W2 = (const float*)d_in[11];
    const float* b2 = (const float*)d_in[12];

    const int N = in_sizes[0] / DD;
    const int E = in_sizes[1] / 2;

    // workspace carve-up
    char* p = (char*)d_ws;
    auto carve = [&](size_t bytes) {
        char* r = p;
        p += (bytes + 255) & ~(size_t)255;
        return r;
    };
    unsigned short* x_bf = (unsigned short*)carve((size_t)N * DD * 2);
    unsigned short* xp_bf = (unsigned short*)carve((size_t)N * DD * 2);
    unsigned short* hn_bf = (unsigned short*)carve((size_t)N * DD * 2);
    float* a_src = (float*)carve((size_t)N * H * 4);
    float* a_dst = (float*)carve((size_t)N * H * 4);
    int* row_ptr = (int*)carve((size_t)(N + 1) * 4);
    int* cnt = (int*)carve((size_t)N * 4);
    int* fill = (int*)carve((size_t)N * 4);
    int* bsum = (int*)carve(256 * 4);
    int* src_sorted = (int*)carve((size_t)E * 4);
    unsigned short* Wt = (unsigned short*)carve(65536 * 2);
    unsigned short* W1t = (unsigned short*)carve(65536 * 2);
    unsigned short* W2t = (unsigned short*)carve(65536 * 2);
    unsigned short* t1_bf = x_bf;  // reuse after GEMM1

    const int n4 = N * DD / 4;
    const int ZB = (N + 255) / 256;  // 196

    // 1. prep: weight transposes + zero cnt/fill + x->bf16
    int prep_blocks = 768 + 2 * ZB + (n4 + 255) / 256;
    prep<<<prep_blocks, 256, 0, stream>>>(x, x_bf, W, Wt, W1, W1t, W2, W2t, cnt, fill, N, n4, ZB);

    dim3 ggrid((N + 127) / 128, 2);

    // 2. xp = x @ W (bf16 out) + fused attention scores
    gemm_bf16<E_NONE, true, true><<<ggrid, 256, 0, stream>>>(
        x_bf, Wt, nullptr, xp_bf, N, att_src, att_dst, a_src, a_dst);

    // 3. CSR build (split, wide launches)
    hist_kernel<<<(E + 255) / 256, 256, 0, stream>>>(edge_index, cnt, E);
    int nb = (N + 1023) / 1024;
    scan_block<<<nb, 1024, 0, stream>>>(cnt, row_ptr, bsum, N);
    scan_partial<<<1, 64, 0, stream>>>(bsum, nb);
    scan_add<<<nb, 1024, 0, stream>>>(row_ptr, bsum, N);
    scatter_kernel<<<(E + 255) / 256, 256, 0, stream>>>(edge_index, row_ptr, fill, src_sorted, E);

    // 4. fused aggregate + LN (bf16 out)
    aggregate_ln<<<(N + 3) / 4, 256, 0, stream>>>(xp_bf, x, a_src, a_dst, row_ptr, src_sorted,
                                                  bias, ln_g, ln_b, hn_bf, N);

    // 5. FFN
    gemm_bf16<E_BIAS_RELU, true, false><<<ggrid, 256, 0, stream>>>(
        hn_bf, W1t, b1, t1_bf, N, nullptr, nullptr, nullptr, nullptr);
    gemm_bf16<E_BIAS, false, false><<<ggrid, 256, 0, stream>>>(
        t1_bf, W2t, b2, d_out, N, nullptr, nullptr, nullptr, nullptr);
}

// Round 5
// 390.340 us; speedup vs baseline: 1.2992x; 1.0137x over previous
//
#include <hip/hip_runtime.h>
#include <hip/hip_bf16.h>

#define H 8
#define HD 32
#define DD 256
#define NEG_SLOPE 0.2f

typedef short bf16x8 __attribute__((ext_vector_type(8)));
typedef float f32x4 __attribute__((ext_vector_type(4)));

__device__ __forceinline__ unsigned short f2bf(float f) {
    unsigned int u = __float_as_uint(f);
    unsigned int r = (u + 0x7fffu + ((u >> 16) & 1u)) >> 16;
    return (unsigned short)r;
}
__device__ __forceinline__ float bf2f(unsigned short b) {
    return __uint_as_float(((unsigned int)b) << 16);
}

#define GLOAD_LDS16(g, s)                                                        \
    __builtin_amdgcn_global_load_lds((const __attribute__((address_space(1))) void*)(g), \
                                     (__attribute__((address_space(3))) void*)(s), 16, 0, 0)

// ---------------- fused prep: weight transposes + zero cnt + conv x ----------
// blocks [0,256) Wt, [256,512) W1t, [512,768) W2t, [768,768+ZB) zero cnt,
// rest conv_x
__global__ __launch_bounds__(256) void prep(const float* __restrict__ x, unsigned short* __restrict__ xb,
                                            const float* __restrict__ W, unsigned short* __restrict__ Wt,
                                            const float* __restrict__ W1, unsigned short* __restrict__ W1t,
                                            const float* __restrict__ W2, unsigned short* __restrict__ W2t,
                                            int* __restrict__ cnt, int N, int n4, int ZB) {
    int b = blockIdx.x;
    int tid = threadIdx.x;
    if (b < 768) {
        const float* src = (b < 256) ? W : (b < 512) ? W1 : W2;
        unsigned short* dst = (b < 256) ? Wt : (b < 512) ? W1t : W2t;
        int i = (b & 255) * 256 + tid;
        int n = i >> 8, k = i & 255;
        dst[i] = f2bf(src[k * 256 + n]);
    } else if (b < 768 + ZB) {
        int i = (b - 768) * 256 + tid;
        if (i < N) cnt[i] = 0;
    } else {
        int i = (b - 768 - ZB) * 256 + tid;
        if (i < n4) {
            float4 v = ((const float4*)x)[i];
            ushort4 o;
            o.x = f2bf(v.x); o.y = f2bf(v.y); o.z = f2bf(v.z); o.w = f2bf(v.w);
            ((ushort4*)xb)[i] = o;
        }
    }
}

// ---------------- fused GEMM: 64 rows x full 256 cols per block --------------
// 4 waves, wave w owns cols [w*64, w*64+64); BK=64 (4 K-iters).
// PHASE2=false: C = A@B1t (+attn scores), bf16 out to global.
// PHASE2=true : t1 = relu(A@B1t + b1) -> LDS; C = t1@B2t + b2, fp32 out.
template <bool ATTN, bool PHASE2>
__global__ __launch_bounds__(256) void gemm_fused(
    const unsigned short* __restrict__ A,
    const unsigned short* __restrict__ B1t, const float* __restrict__ b1,
    const unsigned short* __restrict__ B2t, const float* __restrict__ b2,
    void* __restrict__ Cout, int M,
    const float* __restrict__ att_s, const float* __restrict__ att_d,
    float* __restrict__ a_srcO, float* __restrict__ a_dstO) {
    __shared__ __align__(16) unsigned short Als[4096];              // [q8][64][8]  8KB
    __shared__ __align__(16) unsigned short Bls[16384];             // [q8][256][8] 32KB
    __shared__ __align__(16) unsigned short t1ls[PHASE2 ? 64 * 280 : 8];  // 35KB, stride 280

    const int tid = threadIdx.x;
    const int l = tid & 63;
    const int w = tid >> 6;
    const int r16 = l & 15, q0 = l >> 4;
    const int row0 = blockIdx.x * 64;

    // A staging: 2 chunks/lane; chunk c -> (q8=c>>6, m=c&63); LDS dest = base + lane*16
    const int ca0 = w * 128 + l, ca1 = ca0 + 64;
    const unsigned short* gA0 = A + (size_t)min(row0 + (ca0 & 63), M - 1) * DD + (ca0 >> 6) * 8;
    const unsigned short* gA1 = A + (size_t)min(row0 + (ca1 & 63), M - 1) * DD + (ca1 >> 6) * 8;
    unsigned short* lA0 = &Als[ca0 * 8];
    unsigned short* lA1 = &Als[ca1 * 8];

    // B staging: 8 chunks/lane; chunk c -> (q8=c>>8, n=c&255)
    const unsigned short* gB[8];
    unsigned short* lB[8];
#pragma unroll
    for (int k = 0; k < 8; k++) {
        int c = w * 512 + k * 64 + l;
        gB[k] = B1t + (size_t)(c & 255) * DD + (c >> 8) * 8;
        lB[k] = &Bls[c * 8];
    }

    f32x4 zero = {0.f, 0.f, 0.f, 0.f};
    f32x4 acc[4][4];
#pragma unroll
    for (int i = 0; i < 4; i++)
#pragma unroll
        for (int j = 0; j < 4; j++) acc[i][j] = zero;

    // ---- phase 1 K-loop ----
    for (int kk = 0; kk < 256; kk += 64) {
        GLOAD_LDS16(gA0 + kk, lA0);
        GLOAD_LDS16(gA1 + kk, lA1);
#pragma unroll
        for (int k = 0; k < 8; k++) GLOAD_LDS16(gB[k] + kk, lB[k]);
        __syncthreads();
#pragma unroll
        for (int t = 0; t < 2; t++) {
            int q = t * 4 + q0;
            bf16x8 af[4], bf[4];
#pragma unroll
            for (int i = 0; i < 4; i++)
                af[i] = *(const bf16x8*)&Als[(q * 64 + i * 16 + r16) * 8];
#pragma unroll
            for (int j = 0; j < 4; j++)
                bf[j] = *(const bf16x8*)&Bls[(q * 256 + w * 64 + j * 16 + r16) * 8];
#pragma unroll
            for (int i = 0; i < 4; i++)
#pragma unroll
                for (int j = 0; j < 4; j++)
                    acc[i][j] = __builtin_amdgcn_mfma_f32_16x16x32_bf16(af[i], bf[j], acc[i][j], 0, 0, 0);
        }
        __syncthreads();
    }

    if (!PHASE2) {
        // epilogue: bf16 store + optional attention scores
        float aws0, aws1, aws2, aws3, awd0, awd1, awd2, awd3;
        int hA = 0, hB = 0;
        if (ATTN) {
            hA = w * 2; hB = hA + 1;
            aws0 = att_s[hA * HD + r16];
            aws1 = att_s[hA * HD + 16 + r16];
            aws2 = att_s[hB * HD + r16];
            aws3 = att_s[hB * HD + 16 + r16];
            awd0 = att_d[hA * HD + r16];
            awd1 = att_d[hA * HD + 16 + r16];
            awd2 = att_d[hB * HD + r16];
            awd3 = att_d[hB * HD + 16 + r16];
        }
#pragma unroll
        for (int i = 0; i < 4; i++) {
#pragma unroll
            for (int r = 0; r < 4; r++) {
                int row = row0 + i * 16 + q0 * 4 + r;
                if (row < M) {
#pragma unroll
                    for (int j = 0; j < 4; j++) {
                        int col = w * 64 + j * 16 + r16;
                        ((unsigned short*)Cout)[(size_t)row * DD + col] = f2bf(acc[i][j][r]);
                    }
                }
                if (ATTN) {
                    float v0 = acc[i][0][r], v1 = acc[i][1][r];
                    float v2 = acc[i][2][r], v3 = acc[i][3][r];
                    float ps0 = v0 * aws0 + v1 * aws1;
                    float ps1 = v2 * aws2 + v3 * aws3;
                    float pd0 = v0 * awd0 + v1 * awd1;
                    float pd1 = v2 * awd2 + v3 * awd3;
#pragma unroll
                    for (int m = 1; m < 16; m <<= 1) {
                        ps0 += __shfl_xor(ps0, m, 64);
                        ps1 += __shfl_xor(ps1, m, 64);
                        pd0 += __shfl_xor(pd0, m, 64);
                        pd1 += __shfl_xor(pd1, m, 64);
                    }
                    if (r16 == 0 && row < M) {
                        a_srcO[row * H + hA] = ps0;
                        a_srcO[row * H + hB] = ps1;
                        a_dstO[row * H + hA] = pd0;
                        a_dstO[row * H + hB] = pd1;
                    }
                }
            }
        }
    } else {
        // phase-1 epilogue: t1 = relu(acc + b1) -> LDS (bf16, stride 280)
        float bb1[4];
#pragma unroll
        for (int j = 0; j < 4; j++) bb1[j] = b1[w * 64 + j * 16 + r16];
#pragma unroll
        for (int i = 0; i < 4; i++)
#pragma unroll
            for (int r = 0; r < 4; r++) {
                int rl = i * 16 + q0 * 4 + r;
#pragma unroll
                for (int j = 0; j < 4; j++) {
                    float v = fmaxf(acc[i][j][r] + bb1[j], 0.f);
                    t1ls[rl * 280 + w * 64 + j * 16 + r16] = f2bf(v);
                }
            }
        __syncthreads();  // t1 complete; Bls free for reuse

        // re-point B staging at W2t
        const unsigned short* gB2[8];
#pragma unroll
        for (int k = 0; k < 8; k++) {
            int c = w * 512 + k * 64 + l;
            gB2[k] = B2t + (size_t)(c & 255) * DD + (c >> 8) * 8;
        }
#pragma unroll
        for (int i = 0; i < 4; i++)
#pragma unroll
            for (int j = 0; j < 4; j++) acc[i][j] = zero;

        // ---- phase 2 K-loop: A from t1 LDS, B staged ----
        for (int kk = 0; kk < 256; kk += 64) {
#pragma unroll
            for (int k = 0; k < 8; k++) GLOAD_LDS16(gB2[k] + kk, lB[k]);
            __syncthreads();
#pragma unroll
            for (int t = 0; t < 2; t++) {
                int q = t * 4 + q0;
                bf16x8 af[4], bf[4];
#pragma unroll
                for (int i = 0; i < 4; i++)
                    af[i] = *(const bf16x8*)&t1ls[(i * 16 + r16) * 280 + kk + q * 8];
#pragma unroll
                for (int j = 0; j < 4; j++)
                    bf[j] = *(const bf16x8*)&Bls[(q * 256 + w * 64 + j * 16 + r16) * 8];
#pragma unroll
                for (int i = 0; i < 4; i++)
#pragma unroll
                    for (int j = 0; j < 4; j++)
                        acc[i][j] = __builtin_amdgcn_mfma_f32_16x16x32_bf16(af[i], bf[j], acc[i][j], 0, 0, 0);
            }
            __syncthreads();
        }

        // phase-2 epilogue: fp32 out + b2
        float bb2[4];
#pragma unroll
        for (int j = 0; j < 4; j++) bb2[j] = b2[w * 64 + j * 16 + r16];
#pragma unroll
        for (int i = 0; i < 4; i++)
#pragma unroll
            for (int r = 0; r < 4; r++) {
                int row = row0 + i * 16 + q0 * 4 + r;
                if (row < M) {
#pragma unroll
                    for (int j = 0; j < 4; j++) {
                        int col = w * 64 + j * 16 + r16;
                        ((float*)Cout)[(size_t)row * DD + col] = acc[i][j][r] + bb2[j];
                    }
                }
            }
    }
}

// ---------------- CSR build (split kernels, no fill array) -------------------
__global__ void hist_kernel(const int* __restrict__ ei, int* __restrict__ counts, int E) {
    int e = blockIdx.x * blockDim.x + threadIdx.x;
    if (e < E) atomicAdd(&counts[ei[E + e]], 1);
}

__global__ __launch_bounds__(1024) void scan_block(const int* __restrict__ cnt,
                                                   int* __restrict__ row_ptr,
                                                   int* __restrict__ bsum, int N) {
    __shared__ int ws[16];
    int i = blockIdx.x * 1024 + threadIdx.x;
    int lane = threadIdx.x & 63, w = threadIdx.x >> 6;
    int v = (i < N) ? cnt[i] : 0;
    int sv = v;
#pragma unroll
    for (int off = 1; off < 64; off <<= 1) {
        int t = __shfl_up(sv, off, 64);
        if (lane >= off) sv += t;
    }
    if (lane == 63) ws[w] = sv;
    __syncthreads();
    if (w == 0) {
        int s = (lane < 16) ? ws[lane] : 0;
#pragma unroll
        for (int off = 1; off < 16; off <<= 1) {
            int t = __shfl_up(s, off, 64);
            if (lane >= off) s += t;
        }
        if (lane < 16) ws[lane] = s;
    }
    __syncthreads();
    int incl = sv + ((w > 0) ? ws[w - 1] : 0);
    if (i < N) row_ptr[i + 1] = incl;
    if (threadIdx.x == 1023) bsum[blockIdx.x] = incl;
}

__global__ void scan_partial(int* __restrict__ bsum, int nb) {
    int lane = threadIdx.x;  // 64 threads
    int v = (lane < nb) ? bsum[lane] : 0;
    int s = v;
#pragma unroll
    for (int off = 1; off < 64; off <<= 1) {
        int t = __shfl_up(s, off, 64);
        if (lane >= off) s += t;
    }
    if (lane < nb) bsum[lane] = s - v;  // exclusive
}

__global__ __launch_bounds__(1024) void scan_add(int* __restrict__ row_ptr,
                                                 const int* __restrict__ bsum, int N) {
    int i = blockIdx.x * 1024 + threadIdx.x;
    if (i == 0) row_ptr[0] = 0;
    if (i < N) row_ptr[i + 1] += bsum[blockIdx.x];
}

// scatter consumes row_ptr: after this, row_ptr[d] == end offset of node d,
// and begin(d) == (d>0 ? row_ptr[d-1] : 0).
__global__ void scatter_kernel(const int* __restrict__ ei, int* __restrict__ row_ptr,
                               int* __restrict__ src_sorted, int E) {
    int e = blockIdx.x * blockDim.x + threadIdx.x;
    if (e >= E) return;
    int s = ei[e];
    int d = ei[E + e];
    int pos = atomicAdd(&row_ptr[d], 1);
    src_sorted[pos] = s;
}

// ---------------- fused softmax-aggregate + bias + residual + LN -------------
__global__ __launch_bounds__(256) void aggregate_ln(
    const unsigned short* __restrict__ xp, const unsigned short* __restrict__ x_bf,
    const float* __restrict__ a_src, const float* __restrict__ a_dst,
    const int* __restrict__ rp, const int* __restrict__ src_sorted,
    const float* __restrict__ bias, const float* __restrict__ ln_g,
    const float* __restrict__ ln_b, unsigned short* __restrict__ hn, int N) {
    int wave = threadIdx.x >> 6;
    int lane = threadIdx.x & 63;
    int n = blockIdx.x * 4 + wave;
    if (n >= N) return;
    int h = lane >> 3;

    float adst = a_dst[n * H + h];
    float e0 = a_src[n * H + h] + adst;
    e0 = (e0 > 0.f) ? e0 : NEG_SLOPE * e0;
    float ex = __expf(e0);
    ushort4 u = *(const ushort4*)(xp + (size_t)n * DD + lane * 4);
    float acc0 = ex * bf2f(u.x), acc1 = ex * bf2f(u.y);
    float acc2 = ex * bf2f(u.z), acc3 = ex * bf2f(u.w);
    float denom = ex;

    int beg = (n > 0) ? rp[n - 1] : 0;
    int end = rp[n];
    int i = beg;
    for (; i + 7 < end; i += 8) {
        int s[8];
        float es[8];
        ushort4 uu[8];
#pragma unroll
        for (int k = 0; k < 8; k++) s[k] = src_sorted[i + k];
#pragma unroll
        for (int k = 0; k < 8; k++) es[k] = a_src[s[k] * H + h];
#pragma unroll
        for (int k = 0; k < 8; k++) uu[k] = *(const ushort4*)(xp + (size_t)s[k] * DD + lane * 4);
#pragma unroll
        for (int k = 0; k < 8; k++) {
            float e = es[k] + adst;
            e = (e > 0.f) ? e : NEG_SLOPE * e;
            float wk = __expf(e);
            acc0 += wk * bf2f(uu[k].x);
            acc1 += wk * bf2f(uu[k].y);
            acc2 += wk * bf2f(uu[k].z);
            acc3 += wk * bf2f(uu[k].w);
            denom += wk;
        }
    }
    for (; i < end; i++) {
        int s0 = src_sorted[i];
        float es0 = a_src[s0 * H + h];
        ushort4 u0 = *(const ushort4*)(xp + (size_t)s0 * DD + lane * 4);
        float e0a = es0 + adst;
        e0a = (e0a > 0.f) ? e0a : NEG_SLOPE * e0a;
        float w0 = __expf(e0a);
        acc0 += w0 * bf2f(u0.x);
        acc1 += w0 * bf2f(u0.y);
        acc2 += w0 * bf2f(u0.z);
        acc3 += w0 * bf2f(u0.w);
        denom += w0;
    }
    float inv = 1.f / (denom + 1e-16f);
    float4 bb = *(const float4*)(bias + lane * 4);
    ushort4 xr = *(const ushort4*)(x_bf + (size_t)n * DD + lane * 4);
    float r0 = acc0 * inv + bb.x + bf2f(xr.x);
    float r1 = acc1 * inv + bb.y + bf2f(xr.y);
    float r2 = acc2 * inv + bb.z + bf2f(xr.z);
    float r3 = acc3 * inv + bb.w + bf2f(xr.w);

    float s = r0 + r1 + r2 + r3;
#pragma unroll
    for (int m = 1; m < 64; m <<= 1) s += __shfl_xor(s, m, 64);
    float mu = s * (1.f / 256.f);
    float d0 = r0 - mu, d1 = r1 - mu, d2 = r2 - mu, d3 = r3 - mu;
    float qv = d0 * d0 + d1 * d1 + d2 * d2 + d3 * d3;
#pragma unroll
    for (int m = 1; m < 64; m <<= 1) qv += __shfl_xor(qv, m, 64);
    float rstd = rsqrtf(qv * (1.f / 256.f) + 1e-5f);
    float4 g = *(const float4*)(ln_g + lane * 4);
    float4 b = *(const float4*)(ln_b + lane * 4);
    ushort4 o;
    o.x = f2bf(d0 * rstd * g.x + b.x);
    o.y = f2bf(d1 * rstd * g.y + b.y);
    o.z = f2bf(d2 * rstd * g.z + b.z);
    o.w = f2bf(d3 * rstd * g.w + b.w);
    *(ushort4*)(hn + (size_t)n * DD + lane * 4) = o;
}

// ---------------- launch ------------------------------------------------------
extern "C" void kernel_launch(void* const* d_in, const int* in_sizes, int n_in,
                              void* d_out, int out_size, void* d_ws, size_t ws_size,
                              hipStream_t stream) {
    const float* x = (const float*)d_in[0];
    const int* edge_index = (const int*)d_in[1];
    const float* W = (const float*)d_in[3];
    const float* att_src = (const float*)d_in[4];
    const float* att_dst = (const float*)d_in[5];
    const float* bias = (const float*)d_in[6];
    const float* ln_g = (const float*)d_in[7];
    const float* ln_b = (const float*)d_in[8];
    const float* W1 = (const float*)d_in[9];
    const float* b1 = (const float*)d_in[10];
    const float* W2 = (const float*)d_in[11];
    const float* b2 = (const float*)d_in[12];

    const int N = in_sizes[0] / DD;
    const int E = in_sizes[1] / 2;

    // workspace carve-up
    char* p = (char*)d_ws;
    auto carve = [&](size_t bytes) {
        char* r = p;
        p += (bytes + 255) & ~(size_t)255;
        return r;
    };
    unsigned short* x_bf = (unsigned short*)carve((size_t)N * DD * 2);
    unsigned short* xp_bf = (unsigned short*)carve((size_t)N * DD * 2);
    unsigned short* hn_bf = (unsigned short*)carve((size_t)N * DD * 2);
    float* a_src = (float*)carve((size_t)N * H * 4);
    float* a_dst = (float*)carve((size_t)N * H * 4);
    int* row_ptr = (int*)carve((size_t)(N + 1) * 4);
    int* cnt = (int*)carve((size_t)N * 4);
    int* bsum = (int*)carve(256 * 4);
    int* src_sorted = (int*)carve((size_t)E * 4);
    unsigned short* Wt = (unsigned short*)carve(65536 * 2);
    unsigned short* W1t = (unsigned short*)carve(65536 * 2);
    unsigned short* W2t = (unsigned short*)carve(65536 * 2);

    const int n4 = N * DD / 4;
    const int ZB = (N + 255) / 256;

    // 1. prep: weight transposes + zero cnt + x->bf16
    int prep_blocks = 768 + ZB + (n4 + 255) / 256;
    prep<<<prep_blocks, 256, 0, stream>>>(x, x_bf, W, Wt, W1, W1t, W2, W2t, cnt, N, n4, ZB);

    const int gblocks = (N + 63) / 64;

    // 2. xp = x @ W (bf16 out) + fused attention scores
    gemm_fused<true, false><<<gblocks, 256, 0, stream>>>(
        x_bf, Wt, nullptr, nullptr, nullptr, xp_bf, N, att_src, att_dst, a_src, a_dst);

    // 3. CSR build (split, wide launches)
    hist_kernel<<<(E + 255) / 256, 256, 0, stream>>>(edge_index, cnt, E);
    int nb = (N + 1023) / 1024;
    scan_block<<<nb, 1024, 0, stream>>>(cnt, row_ptr, bsum, N);
    scan_partial<<<1, 64, 0, stream>>>(bsum, nb);
    scan_add<<<nb, 1024, 0, stream>>>(row_ptr, bsum, N);
    scatter_kernel<<<(E + 255) / 256, 256, 0, stream>>>(edge_index, row_ptr, src_sorted, E);

    // 4. fused aggregate + LN (bf16 out)
    aggregate_ln<<<(N + 3) / 4, 256, 0, stream>>>(xp_bf, x_bf, a_src, a_dst, row_ptr, src_sorted,
                                                  bias, ln_g, ln_b, hn_bf, N);

    // 5. fused FFN: out = relu(hn@W1+b1)@W2 + b2  (one launch, t1 stays in LDS)
    gemm_fused<false, true><<<gblocks, 256, 0, stream>>>(
        hn_bf, W1t, b1, W2t, b2, d_out, N, nullptr, nullptr, nullptr, nullptr);
}